// Round 4
// baseline (439.311 us; speedup 1.0000x reference)
//
#include <hip/hip_runtime.h>
#include <math.h>

#define BN_EPS 1e-5f

constexpr int B  = 4;
constexpr int C  = 256;
constexpr int HW = 4096;   // 64*64
constexpr int CK = 64;
constexpr int CV = 256;
constexpr int CO = 320;    // CK + CV
constexpr int CHG = 2;     // channel groups in attn (128 ch each)

typedef short bf16x8 __attribute__((ext_vector_type(8)));
typedef float f32x4  __attribute__((ext_vector_type(4)));

__device__ __forceinline__ ushort f2bf(float f) {
    unsigned u = __float_as_uint(f);
    u += 0x7FFFu + ((u >> 16) & 1u);      // round to nearest even
    return (ushort)(u >> 16);
}

// ---------------------------------------------------------------------------
// Kernel 0: fold BN into Wk (row-scale) and emit bf16 weight table
// ---------------------------------------------------------------------------
__global__ __launch_bounds__(256) void wprep(
    const float* __restrict__ Wk, const float* __restrict__ bk,
    const float* __restrict__ gamma, const float* __restrict__ beta,
    const float* __restrict__ mean,  const float* __restrict__ var,
    const float* __restrict__ Wv, const float* __restrict__ bv,
    ushort* __restrict__ Wq, float* __restrict__ bq)
{
    const int co = blockIdx.x;
    const int c  = threadIdx.x;
    float w;
    if (co < CK) {
        float inv = gamma[co] * rsqrtf(var[co] + BN_EPS);
        w = Wk[co * C + c] * inv;
        if (c == 0) bq[co] = bk[co] * inv + (beta[co] - mean[co] * inv);
    } else {
        w = Wv[(co - CK) * C + c];
        if (c == 0) bq[co] = bv[co - CK];
    }
    Wq[co * C + c] = f2bf(w);
}

// ---------------------------------------------------------------------------
// Kernel 1: KV projection as MFMA GEMM + fused K-norms (Cauchy-Schwarz bound).
// ---------------------------------------------------------------------------
__global__ __launch_bounds__(256) void kv_gemm(
    const float* __restrict__ x, const ushort* __restrict__ Wq,
    const float* __restrict__ bq,
    ushort* __restrict__ Kbuf, ushort* __restrict__ Vbuf,
    float* __restrict__ mb, unsigned* __restrict__ Mx)
{
    __shared__ __align__(16) ushort xt[32][C + 8];   // [hw][c] bf16, pad 8

    const int t    = threadIdx.x;
    const int lane = t & 63;
    const int wv   = t >> 6;
    const int q    = lane >> 4;
    const int col  = lane & 15;
    const int hw0  = blockIdx.x * 32;
    const int b    = blockIdx.y;

    const float* xb = x + (size_t)b * C * HW;

    // stage x tile: strided dword loads -> pack bf16x4 -> b64 LDS write
    {
        const int cq  = (t >> 5) * 4;    // 0,4,...,28
        const int hwo = t & 31;
#pragma unroll
        for (int pass = 0; pass < 8; pass++) {
            const int c0 = pass * 32;
            float a0 = xb[(size_t)(c0 + cq + 0) * HW + hw0 + hwo];
            float a1 = xb[(size_t)(c0 + cq + 1) * HW + hw0 + hwo];
            float a2 = xb[(size_t)(c0 + cq + 2) * HW + hw0 + hwo];
            float a3 = xb[(size_t)(c0 + cq + 3) * HW + hw0 + hwo];
            ushort4 u = make_ushort4(f2bf(a0), f2bf(a1), f2bf(a2), f2bf(a3));
            *(ushort4*)&xt[hwo][c0 + cq] = u;
        }
    }
    __syncthreads();

    f32x4 acc[5][2];
#pragma unroll
    for (int mi = 0; mi < 5; mi++)
#pragma unroll
        for (int nt = 0; nt < 2; nt++)
            acc[mi][nt] = (f32x4){0.f, 0.f, 0.f, 0.f};

#pragma unroll
    for (int ks = 0; ks < 8; ks++) {
        bf16x8 av[5], bvv[2];
#pragma unroll
        for (int mi = 0; mi < 5; mi++)
            av[mi] = *(const bf16x8*)(Wq + (size_t)(wv * 80 + mi * 16 + col) * C + ks * 32 + q * 8);
#pragma unroll
        for (int nt = 0; nt < 2; nt++)
            bvv[nt] = *(const bf16x8*)&xt[nt * 16 + col][ks * 32 + q * 8];
#pragma unroll
        for (int mi = 0; mi < 5; mi++)
#pragma unroll
            for (int nt = 0; nt < 2; nt++)
                acc[mi][nt] = __builtin_amdgcn_mfma_f32_16x16x32_bf16(av[mi], bvv[nt], acc[mi][nt], 0, 0, 0);
    }

    float ssq[2] = {0.f, 0.f};
#pragma unroll
    for (int mi = 0; mi < 5; mi++) {
        const int cot = wv * 80 + mi * 16;
        float bi[4];
#pragma unroll
        for (int r = 0; r < 4; r++) bi[r] = bq[cot + q * 4 + r];
#pragma unroll
        for (int nt = 0; nt < 2; nt++) {
            const int hw = hw0 + nt * 16 + col;
            float v0 = acc[mi][nt][0] + bi[0];
            float v1 = acc[mi][nt][1] + bi[1];
            float v2 = acc[mi][nt][2] + bi[2];
            float v3 = acc[mi][nt][3] + bi[3];
            if (cot < CK) {           // K tiles: transposed b64 store
                ushort4 kk = make_ushort4(f2bf(v0), f2bf(v1), f2bf(v2), f2bf(v3));
                *(ushort4*)&Kbuf[((size_t)b * HW + hw) * CK + cot + q * 4] = kk;
                ssq[nt] += v0 * v0 + v1 * v1 + v2 * v2 + v3 * v3;
            } else {
                const int cv = cot - CK + q * 4;
                Vbuf[((size_t)b * CV + cv + 0) * HW + hw] = f2bf(v0);
                Vbuf[((size_t)b * CV + cv + 1) * HW + hw] = f2bf(v1);
                Vbuf[((size_t)b * CV + cv + 2) * HW + hw] = f2bf(v2);
                Vbuf[((size_t)b * CV + cv + 3) * HW + hw] = f2bf(v3);
            }
        }
    }

    if (wv == 0) {
        float mxn = 0.f;
#pragma unroll
        for (int nt = 0; nt < 2; nt++) {
            float ss = ssq[nt];
            ss += __shfl_xor(ss, 16, 64);
            ss += __shfl_xor(ss, 32, 64);
            float nr = sqrtf(ss);
            if (lane < 16) mb[(size_t)b * HW + hw0 + nt * 16 + col] = nr;
            mxn = fmaxf(mxn, nr);
        }
#pragma unroll
        for (int off = 1; off <= 32; off <<= 1)
            mxn = fmaxf(mxn, __shfl_xor(mxn, off, 64));
        if (t == 0) atomicMax(Mx + b, __float_as_uint(mxn));
    }
}

// ---------------------------------------------------------------------------
// Kernel 2: MFMA flash attention, bound-softmax. R9: ZERO-BARRIER design.
//
// Insight: after swapped QK^T with j-permuted K A-frags, lane (q,col) holds
// p for i = (its wave's) col and j = q*8+{0..7}, 32+q*8+{0..7} -- exactly
// the PV B-operand fragment for its own i-group. So each wave now computes
// PV for its OWN 16 i's over ALL 128 c (mt 0..7): P never leaves registers.
//   - no LDS, no __syncthreads, no vmcnt(0) drains, no wave convoy
//   - V/K frags 4x-redundant across waves, but L2-resident per XCD
//     (combo = xcd: V-half 1MB + K 512KB = 1.5MB < 4MB L2)
//   - JS=1: 512 blocks = exactly 2/CU; every out element single-writer ->
//     plain stores with fused 1/l division; norm_out/Lbuf/atomics deleted
// ---------------------------------------------------------------------------
#define ATTN_TILE(KC, KN, JC, JN)                                              \
    {                                                                          \
        const int jc_ = (JC), jn_ = (JN);                                      \
        _Pragma("unroll")                                                      \
        for (int nt = 0; nt < 4; nt++)                                         \
            _Pragma("unroll")                                                  \
            for (int k = 0; k < 2; k++)                                        \
                KN[nt][k] = *(const bf16x8*)(Kb + (size_t)(jn_ + jperm + (nt >> 1) * 32 + (nt & 1) * 4) * CK + k * 32 + q * 8); \
        bf16x8 vf[8][2];                                                       \
        _Pragma("unroll")                                                      \
        for (int mt = 0; mt < 8; mt++)                                         \
            _Pragma("unroll")                                                  \
            for (int kk = 0; kk < 2; kk++)                                     \
                vf[mt][kk] = *(const bf16x8*)(Vb + (size_t)(cbase + mt * 16 + col) * HW + jc_ + kk * 32 + q * 8); \
        f32x4 S[4];                                                            \
        __builtin_amdgcn_s_setprio(1);                                         \
        _Pragma("unroll")                                                      \
        for (int nt = 0; nt < 4; nt++) {                                       \
            S[nt] = __builtin_amdgcn_mfma_f32_16x16x32_bf16(KC[nt][0], qa[0], zf, 0, 0, 0); \
            S[nt] = __builtin_amdgcn_mfma_f32_16x16x32_bf16(KC[nt][1], qa[1], S[nt], 0, 0, 0); \
        }                                                                      \
        __builtin_amdgcn_s_setprio(0);                                         \
        bf16x8 w0, w1;                                                         \
        _Pragma("unroll")                                                      \
        for (int nt = 0; nt < 4; nt++) {                                       \
            float p0 = __expf(S[nt][0] - m_val);                               \
            float p1 = __expf(S[nt][1] - m_val);                               \
            float p2 = __expf(S[nt][2] - m_val);                               \
            float p3 = __expf(S[nt][3] - m_val);                               \
            l_acc += (p0 + p1) + (p2 + p3);                                    \
            if (nt == 0) {                                                     \
                w0[0] = (short)f2bf(p0); w0[1] = (short)f2bf(p1);              \
                w0[2] = (short)f2bf(p2); w0[3] = (short)f2bf(p3);              \
            } else if (nt == 1) {                                              \
                w0[4] = (short)f2bf(p0); w0[5] = (short)f2bf(p1);              \
                w0[6] = (short)f2bf(p2); w0[7] = (short)f2bf(p3);              \
            } else if (nt == 2) {                                              \
                w1[0] = (short)f2bf(p0); w1[1] = (short)f2bf(p1);              \
                w1[2] = (short)f2bf(p2); w1[3] = (short)f2bf(p3);              \
            } else {                                                           \
                w1[4] = (short)f2bf(p0); w1[5] = (short)f2bf(p1);              \
                w1[6] = (short)f2bf(p2); w1[7] = (short)f2bf(p3);              \
            }                                                                  \
        }                                                                      \
        __builtin_amdgcn_s_setprio(1);                                         \
        _Pragma("unroll")                                                      \
        for (int mt = 0; mt < 8; mt++) {                                       \
            Oacc[mt] = __builtin_amdgcn_mfma_f32_16x16x32_bf16(vf[mt][0], w0, Oacc[mt], 0, 0, 0); \
            Oacc[mt] = __builtin_amdgcn_mfma_f32_16x16x32_bf16(vf[mt][1], w1, Oacc[mt], 0, 0, 0); \
        }                                                                      \
        __builtin_amdgcn_s_setprio(0);                                         \
    }

__global__ __launch_bounds__(256, 2) void attn_kernel(
    const ushort* __restrict__ Kbuf, const ushort* __restrict__ Vbuf,
    const float* __restrict__ mb, const unsigned* __restrict__ Mx,
    float* __restrict__ out)
{
    const int t    = threadIdx.x;
    const int lane = t & 63;
    const int wv   = t >> 6;          // 0..3 : i-group within block
    const int q    = lane >> 4;       // quad 0..3
    const int col  = lane & 15;

    // --- XCD-partition remap (bijective on the 512-block grid) ---
    // lin%8 == XCD (round-robin dispatch). combo = xcd: each XCD owns one
    // (chg,b) pair -> working set 1.5 MB < 4 MB per-XCD L2.
    const unsigned lin = blockIdx.x + 64u * (blockIdx.y + (unsigned)CHG * blockIdx.z);
    const int xcd   = lin & 7;
    const int s_    = lin >> 3;              // 0..63
    const int i0g   = s_ * 64;
    const int chg   = xcd & 1;
    const int b     = xcd >> 1;              // 0..3

    const int iw    = wv * 16 + col;         // local i row (0..63)
    const int jperm = (col >> 2) * 8 + (col & 3);  // j-row permutation base

    const ushort* Kb = Kbuf + (size_t)b * HW * CK;
    const ushort* Vb = Vbuf + (size_t)b * CV * HW;

    // Q B-frags: B[k=ck][n=i], n = col -> i = i0g + iw
    bf16x8 qa[2];
#pragma unroll
    for (int k = 0; k < 2; k++)
        qa[k] = *(const bf16x8*)(Kb + (size_t)(i0g + iw) * CK + k * 32 + q * 8);

    // per-row exp bound (Cauchy-Schwarz): one scalar per lane
    const float Mxf = __uint_as_float(Mx[b]);
    const float m_val = mb[(size_t)b * HW + i0g + iw] * Mxf;

    f32x4 Oacc[8];
#pragma unroll
    for (int mt = 0; mt < 8; mt++)
        Oacc[mt] = (f32x4){0.f, 0.f, 0.f, 0.f};

    float l_acc = 0.f;
    const f32x4 zf = (f32x4){0.f, 0.f, 0.f, 0.f};
    const int cbase = chg * 128;

    // preload K tile 0 (static dbuf, rows j-permuted)
    bf16x8 kf0[4][2], kf1[4][2];
#pragma unroll
    for (int nt = 0; nt < 4; nt++)
#pragma unroll
        for (int k = 0; k < 2; k++)
            kf0[nt][k] = *(const bf16x8*)(Kb + (size_t)(jperm + (nt >> 1) * 32 + (nt & 1) * 4) * CK + k * 32 + q * 8);

    for (int j0 = 0; j0 < HW; j0 += 128) {
        ATTN_TILE(kf0, kf1, j0,      j0 + 64);
        ATTN_TILE(kf1, kf0, j0 + 64, (j0 + 128) & (HW - 1));
    }

    // row sum l for i = i0g+iw: reduce across the 4 quad-groups (all lanes get it)
    l_acc += __shfl_xor(l_acc, 16, 64);
    l_acc += __shfl_xor(l_acc, 32, 64);
    const float inv = 1.0f / l_acc;

    // O store (single-writer: js removed, chg disjoint): fused division
    float* ob = out + (size_t)b * CV * HW;
#pragma unroll
    for (int mt = 0; mt < 8; mt++)
#pragma unroll
        for (int r = 0; r < 4; r++)
            ob[(size_t)(cbase + mt * 16 + q * 4 + r) * HW + i0g + iw] = Oacc[mt][r] * inv;
}

// ---------------------------------------------------------------------------
extern "C" void kernel_launch(void* const* d_in, const int* in_sizes, int n_in,
                              void* d_out, int out_size, void* d_ws, size_t ws_size,
                              hipStream_t stream)
{
    const float* x     = (const float*)d_in[0];
    const float* Wk    = (const float*)d_in[1];
    const float* bk    = (const float*)d_in[2];
    const float* gamma = (const float*)d_in[3];
    const float* beta  = (const float*)d_in[4];
    const float* mean  = (const float*)d_in[5];
    const float* var   = (const float*)d_in[6];
    const float* Wv    = (const float*)d_in[7];
    const float* bv    = (const float*)d_in[8];
    float* out = (float*)d_out;

    ushort*   Kbuf = (ushort*)d_ws;                          // [B][HW][CK]  2 MB
    ushort*   Vbuf = Kbuf + (size_t)B * HW * CK;             // [B][CV][HW]  8.4 MB
    ushort*   Wq   = Vbuf + (size_t)B * CV * HW;             // [320][256]   160 KB
    float*    bq   = (float*)(Wq + (size_t)CO * C);          // [320]
    float*    mb   = bq + CO;                                // [B][HW]
    unsigned* Mx   = (unsigned*)(mb + (size_t)B * HW);       // [B]

    hipMemsetAsync(Mx, 0, B * sizeof(unsigned), stream);

    wprep<<<dim3(CO), 256, 0, stream>>>(Wk, bk, gamma, beta, mean, var, Wv, bv, Wq, bq);

    kv_gemm<<<dim3(HW / 32, B), 256, 0, stream>>>(x, Wq, bq, Kbuf, Vbuf, mb, Mx);

    dim3 g2(HW / 64, CHG, B);                                // (64,2,4) = 512 blocks
    attn_kernel<<<g2, 256, 0, stream>>>(Kbuf, Vbuf, mb, Mx, out);
}

// Round 5
// 180.223 us; speedup vs baseline: 2.4376x; 2.4376x over previous
//
#include <hip/hip_runtime.h>
#include <math.h>

#define BN_EPS 1e-5f

constexpr int B  = 4;
constexpr int C  = 256;
constexpr int HW = 4096;   // 64*64
constexpr int CK = 64;
constexpr int CV = 256;
constexpr int CO = 320;    // CK + CV
constexpr int CHG = 2;     // channel groups in attn (128 ch each)

typedef short bf16x8 __attribute__((ext_vector_type(8)));
typedef float f32x4  __attribute__((ext_vector_type(4)));

__device__ __forceinline__ ushort f2bf(float f) {
    unsigned u = __float_as_uint(f);
    u += 0x7FFFu + ((u >> 16) & 1u);      // round to nearest even
    return (ushort)(u >> 16);
}

// byte-XOR swizzles (applied identically to pre-swizzled global source and
// LDS read -> involution, bijective within each 128-B row)
__device__ __forceinline__ int swzk(int r) {
    return (((r & 3) | ((((r >> 2) ^ (r >> 3)) & 1) << 2)) << 4);
}
__device__ __forceinline__ int swzv(int r) { return (r & 7) << 4; }

__device__ __forceinline__ void gload_lds16(const void* g, void* l) {
    __builtin_amdgcn_global_load_lds(
        (const __attribute__((address_space(1))) unsigned*)g,
        (__attribute__((address_space(3))) unsigned*)l, 16, 0, 0);
}

// ---------------------------------------------------------------------------
// Kernel 0: fold BN into Wk (row-scale) and emit bf16 weight table
// ---------------------------------------------------------------------------
__global__ __launch_bounds__(256) void wprep(
    const float* __restrict__ Wk, const float* __restrict__ bk,
    const float* __restrict__ gamma, const float* __restrict__ beta,
    const float* __restrict__ mean,  const float* __restrict__ var,
    const float* __restrict__ Wv, const float* __restrict__ bv,
    ushort* __restrict__ Wq, float* __restrict__ bq)
{
    const int co = blockIdx.x;
    const int c  = threadIdx.x;
    float w;
    if (co < CK) {
        float inv = gamma[co] * rsqrtf(var[co] + BN_EPS);
        w = Wk[co * C + c] * inv;
        if (c == 0) bq[co] = bk[co] * inv + (beta[co] - mean[co] * inv);
    } else {
        w = Wv[(co - CK) * C + c];
        if (c == 0) bq[co] = bv[co - CK];
    }
    Wq[co * C + c] = f2bf(w);
}

// ---------------------------------------------------------------------------
// Kernel 1: KV projection as MFMA GEMM + fused K-norms (Cauchy-Schwarz bound).
// ---------------------------------------------------------------------------
__global__ __launch_bounds__(256) void kv_gemm(
    const float* __restrict__ x, const ushort* __restrict__ Wq,
    const float* __restrict__ bq,
    ushort* __restrict__ Kbuf, ushort* __restrict__ Vbuf,
    float* __restrict__ mb, unsigned* __restrict__ Mx)
{
    __shared__ __align__(16) ushort xt[32][C + 8];   // [hw][c] bf16, pad 8

    const int t    = threadIdx.x;
    const int lane = t & 63;
    const int wv   = t >> 6;
    const int q    = lane >> 4;
    const int col  = lane & 15;
    const int hw0  = blockIdx.x * 32;
    const int b    = blockIdx.y;

    const float* xb = x + (size_t)b * C * HW;

    // stage x tile: strided dword loads -> pack bf16x4 -> b64 LDS write
    {
        const int cq  = (t >> 5) * 4;    // 0,4,...,28
        const int hwo = t & 31;
#pragma unroll
        for (int pass = 0; pass < 8; pass++) {
            const int c0 = pass * 32;
            float a0 = xb[(size_t)(c0 + cq + 0) * HW + hw0 + hwo];
            float a1 = xb[(size_t)(c0 + cq + 1) * HW + hw0 + hwo];
            float a2 = xb[(size_t)(c0 + cq + 2) * HW + hw0 + hwo];
            float a3 = xb[(size_t)(c0 + cq + 3) * HW + hw0 + hwo];
            ushort4 u = make_ushort4(f2bf(a0), f2bf(a1), f2bf(a2), f2bf(a3));
            *(ushort4*)&xt[hwo][c0 + cq] = u;
        }
    }
    __syncthreads();

    f32x4 acc[5][2];
#pragma unroll
    for (int mi = 0; mi < 5; mi++)
#pragma unroll
        for (int nt = 0; nt < 2; nt++)
            acc[mi][nt] = (f32x4){0.f, 0.f, 0.f, 0.f};

#pragma unroll
    for (int ks = 0; ks < 8; ks++) {
        bf16x8 av[5], bvv[2];
#pragma unroll
        for (int mi = 0; mi < 5; mi++)
            av[mi] = *(const bf16x8*)(Wq + (size_t)(wv * 80 + mi * 16 + col) * C + ks * 32 + q * 8);
#pragma unroll
        for (int nt = 0; nt < 2; nt++)
            bvv[nt] = *(const bf16x8*)&xt[nt * 16 + col][ks * 32 + q * 8];
#pragma unroll
        for (int mi = 0; mi < 5; mi++)
#pragma unroll
            for (int nt = 0; nt < 2; nt++)
                acc[mi][nt] = __builtin_amdgcn_mfma_f32_16x16x32_bf16(av[mi], bvv[nt], acc[mi][nt], 0, 0, 0);
    }

    float ssq[2] = {0.f, 0.f};
#pragma unroll
    for (int mi = 0; mi < 5; mi++) {
        const int cot = wv * 80 + mi * 16;
        float bi[4];
#pragma unroll
        for (int r = 0; r < 4; r++) bi[r] = bq[cot + q * 4 + r];
#pragma unroll
        for (int nt = 0; nt < 2; nt++) {
            const int hw = hw0 + nt * 16 + col;
            float v0 = acc[mi][nt][0] + bi[0];
            float v1 = acc[mi][nt][1] + bi[1];
            float v2 = acc[mi][nt][2] + bi[2];
            float v3 = acc[mi][nt][3] + bi[3];
            if (cot < CK) {           // K tiles: transposed b64 store
                ushort4 kk = make_ushort4(f2bf(v0), f2bf(v1), f2bf(v2), f2bf(v3));
                *(ushort4*)&Kbuf[((size_t)b * HW + hw) * CK + cot + q * 4] = kk;
                ssq[nt] += v0 * v0 + v1 * v1 + v2 * v2 + v3 * v3;
            } else {
                const int cv = cot - CK + q * 4;
                Vbuf[((size_t)b * CV + cv + 0) * HW + hw] = f2bf(v0);
                Vbuf[((size_t)b * CV + cv + 1) * HW + hw] = f2bf(v1);
                Vbuf[((size_t)b * CV + cv + 2) * HW + hw] = f2bf(v2);
                Vbuf[((size_t)b * CV + cv + 3) * HW + hw] = f2bf(v3);
            }
        }
    }

    if (wv == 0) {
        float mxn = 0.f;
#pragma unroll
        for (int nt = 0; nt < 2; nt++) {
            float ss = ssq[nt];
            ss += __shfl_xor(ss, 16, 64);
            ss += __shfl_xor(ss, 32, 64);
            float nr = sqrtf(ss);
            if (lane < 16) mb[(size_t)b * HW + hw0 + nt * 16 + col] = nr;
            mxn = fmaxf(mxn, nr);
        }
#pragma unroll
        for (int off = 1; off <= 32; off <<= 1)
            mxn = fmaxf(mxn, __shfl_xor(mxn, off, 64));
        if (t == 0) atomicMax(Mx + b, __float_as_uint(mxn));
    }
}

// ---------------------------------------------------------------------------
// Kernel 2: MFMA flash attention, bound-softmax. R10: zero-P-exchange (R9's
// verified fragment algebra: lane's S output IS its PV B-fragment) + LDS
// K/V staging via coalesced global_load_lds.
//
// R9 post-mortem: time scales with # of address-divergent VMEM loads
// (~300 cy each; 12 loads/tile -> 194us, 24 -> 355us). Fix: stage the 64-j
// K tile (8 KB, contiguous) + V tile (16 KB, 128-B rows) per block via 6
// global_load_lds(16B) per thread (coalesced), read fragments with
// swizzled ds_read_b128 (conflict-free per 8-lane group; swzk/swzv applied
// to pre-swizzled global source AND read -> involution). LDS double-buffer,
// ONE barrier per tile; stage issued at tile top gets full-tile window
// before the barrier's vmcnt drain.
// ---------------------------------------------------------------------------
__global__ __launch_bounds__(256, 2) void attn_kernel(
    const ushort* __restrict__ Kbuf, const ushort* __restrict__ Vbuf,
    const float* __restrict__ mb, const unsigned* __restrict__ Mx,
    float* __restrict__ out)
{
    __shared__ __align__(16) ushort Kt[2][64 * 64];    // 8 KB per buf
    __shared__ __align__(16) ushort Vt[2][128 * 64];   // 16 KB per buf

    const int t    = threadIdx.x;
    const int lane = t & 63;
    const int wv   = t >> 6;          // 0..3 : i-group within block
    const int q    = lane >> 4;       // quad 0..3
    const int col  = lane & 15;

    // --- XCD-partition remap (bijective on the 512-block grid) ---
    const unsigned lin = blockIdx.x + 64u * (blockIdx.y + (unsigned)CHG * blockIdx.z);
    const int xcd   = lin & 7;
    const int s_    = lin >> 3;              // 0..63
    const int i0g   = s_ * 64;
    const int chg   = xcd & 1;
    const int b     = xcd >> 1;              // 0..3

    const int iw    = wv * 16 + col;         // local i row (0..63)
    const int jperm = (col >> 2) * 8 + (col & 3);  // j-row permutation base

    const ushort* Kb = Kbuf + (size_t)b * HW * CK;
    const ushort* Vb = Vbuf + (size_t)b * CV * HW;
    const int cbase = chg * 128;

    // Q B-frags: B[k=ck][n=i], n = col -> i = i0g + iw (one-time scattered)
    bf16x8 qa[2];
#pragma unroll
    for (int k = 0; k < 2; k++)
        qa[k] = *(const bf16x8*)(Kb + (size_t)(i0g + iw) * CK + k * 32 + q * 8);

    // per-row exp bound (Cauchy-Schwarz): one scalar per lane
    const float Mxf = __uint_as_float(Mx[b]);
    const float m_val = mb[(size_t)b * HW + i0g + iw] * Mxf;

    f32x4 Oacc[8];
#pragma unroll
    for (int mt = 0; mt < 8; mt++)
        Oacc[mt] = (f32x4){0.f, 0.f, 0.f, 0.f};

    float l_acc = 0.f;
    const f32x4 zf = (f32x4){0.f, 0.f, 0.f, 0.f};

    // ---- staging: K tile 8 KB (2 chunks/wave), V tile 16 KB (4 chunks/wave)
    // LDS dest linear (rule 21); global source pre-swizzled.
#define STAGE(BUF, JN)                                                         \
    {                                                                          \
        const int jn_s = (JN);                                                 \
        _Pragma("unroll")                                                      \
        for (int p = 0; p < 2; p++) {                                          \
            int off = (wv * 2 + p) * 1024 + lane * 16;                         \
            int r = off >> 7, cb = off & 127;                                  \
            const char* g = (const char*)Kb + (size_t)(jn_s + r) * 128         \
                            + (cb ^ swzk(r));                                  \
            gload_lds16(g, (char*)&Kt[BUF][0] + off);                          \
        }                                                                      \
        _Pragma("unroll")                                                      \
        for (int p = 0; p < 4; p++) {                                          \
            int off = (wv * 4 + p) * 1024 + lane * 16;                         \
            int r = off >> 7, cb = off & 127;                                  \
            const char* g = (const char*)Vb                                    \
                            + ((size_t)(cbase + r) * HW + jn_s) * 2            \
                            + (cb ^ swzv(r));                                  \
            gload_lds16(g, (char*)&Vt[BUF][0] + off);                          \
        }                                                                      \
    }

    // prologue: stage tile 0 into buf 0
    STAGE(0, 0);
    __syncthreads();

    int cur = 0;
    for (int j0 = 0; j0 < HW; j0 += 64) {
        // issue next tile's staging first (full-tile latency window)
        STAGE(cur ^ 1, (j0 + 64) & (HW - 1));

        const char* KtB = (const char*)&Kt[cur][0];
        const char* VtB = (const char*)&Vt[cur][0];

        // S^T = mfma(K, Q): K A-frags from LDS (jperm rows, swizzled)
        f32x4 S[4];
        __builtin_amdgcn_s_setprio(1);
#pragma unroll
        for (int nt = 0; nt < 4; nt++) {
            const int jr = jperm + (nt >> 1) * 32 + (nt & 1) * 4;
            bf16x8 k0 = *(const bf16x8*)(KtB + jr * 128 + ((q * 16) ^ swzk(jr)));
            bf16x8 k1 = *(const bf16x8*)(KtB + jr * 128 + ((64 + q * 16) ^ swzk(jr)));
            S[nt] = __builtin_amdgcn_mfma_f32_16x16x32_bf16(k0, qa[0], zf, 0, 0, 0);
            S[nt] = __builtin_amdgcn_mfma_f32_16x16x32_bf16(k1, qa[1], S[nt], 0, 0, 0);
        }
        __builtin_amdgcn_s_setprio(0);

        // exp + pack into PV B-fragments (register P, R9-verified layout)
        bf16x8 w0, w1;
#pragma unroll
        for (int nt = 0; nt < 4; nt++) {
            float p0 = __expf(S[nt][0] - m_val);
            float p1 = __expf(S[nt][1] - m_val);
            float p2 = __expf(S[nt][2] - m_val);
            float p3 = __expf(S[nt][3] - m_val);
            l_acc += (p0 + p1) + (p2 + p3);
            if (nt == 0) {
                w0[0] = (short)f2bf(p0); w0[1] = (short)f2bf(p1);
                w0[2] = (short)f2bf(p2); w0[3] = (short)f2bf(p3);
            } else if (nt == 1) {
                w0[4] = (short)f2bf(p0); w0[5] = (short)f2bf(p1);
                w0[6] = (short)f2bf(p2); w0[7] = (short)f2bf(p3);
            } else if (nt == 2) {
                w1[0] = (short)f2bf(p0); w1[1] = (short)f2bf(p1);
                w1[2] = (short)f2bf(p2); w1[3] = (short)f2bf(p3);
            } else {
                w1[4] = (short)f2bf(p0); w1[5] = (short)f2bf(p1);
                w1[6] = (short)f2bf(p2); w1[7] = (short)f2bf(p3);
            }
        }

        // PV: V B-frags from LDS (row = c, swizzled), 2 MFMA per mt
        __builtin_amdgcn_s_setprio(1);
#pragma unroll
        for (int mt = 0; mt < 8; mt++) {
            const int vr = mt * 16 + col;
            bf16x8 v0 = *(const bf16x8*)(VtB + vr * 128 + ((q * 16) ^ swzv(vr)));
            bf16x8 v1 = *(const bf16x8*)(VtB + vr * 128 + ((64 + q * 16) ^ swzv(vr)));
            Oacc[mt] = __builtin_amdgcn_mfma_f32_16x16x32_bf16(v0, w0, Oacc[mt], 0, 0, 0);
            Oacc[mt] = __builtin_amdgcn_mfma_f32_16x16x32_bf16(v1, w1, Oacc[mt], 0, 0, 0);
        }
        __builtin_amdgcn_s_setprio(0);

        __syncthreads();   // buf ready-to-overwrite + next stage completed
        cur ^= 1;
    }
#undef STAGE

    // row sum l for i = i0g+iw: reduce across the 4 quad-groups
    l_acc += __shfl_xor(l_acc, 16, 64);
    l_acc += __shfl_xor(l_acc, 32, 64);
    const float inv = 1.0f / l_acc;

    // O store (single-writer; chg disjoint): fused division
    float* ob = out + (size_t)b * CV * HW;
#pragma unroll
    for (int mt = 0; mt < 8; mt++)
#pragma unroll
        for (int r = 0; r < 4; r++)
            ob[(size_t)(cbase + mt * 16 + q * 4 + r) * HW + i0g + iw] = Oacc[mt][r] * inv;
}

// ---------------------------------------------------------------------------
extern "C" void kernel_launch(void* const* d_in, const int* in_sizes, int n_in,
                              void* d_out, int out_size, void* d_ws, size_t ws_size,
                              hipStream_t stream)
{
    const float* x     = (const float*)d_in[0];
    const float* Wk    = (const float*)d_in[1];
    const float* bk    = (const float*)d_in[2];
    const float* gamma = (const float*)d_in[3];
    const float* beta  = (const float*)d_in[4];
    const float* mean  = (const float*)d_in[5];
    const float* var   = (const float*)d_in[6];
    const float* Wv    = (const float*)d_in[7];
    const float* bv    = (const float*)d_in[8];
    float* out = (float*)d_out;

    ushort*   Kbuf = (ushort*)d_ws;                          // [B][HW][CK]  2 MB
    ushort*   Vbuf = Kbuf + (size_t)B * HW * CK;             // [B][CV][HW]  8.4 MB
    ushort*   Wq   = Vbuf + (size_t)B * CV * HW;             // [320][256]   160 KB
    float*    bq   = (float*)(Wq + (size_t)CO * C);          // [320]
    float*    mb   = bq + CO;                                // [B][HW]
    unsigned* Mx   = (unsigned*)(mb + (size_t)B * HW);       // [B]

    hipMemsetAsync(Mx, 0, B * sizeof(unsigned), stream);

    wprep<<<dim3(CO), 256, 0, stream>>>(Wk, bk, gamma, beta, mean, var, Wv, bv, Wq, bq);

    kv_gemm<<<dim3(HW / 32, B), 256, 0, stream>>>(x, Wq, bq, Kbuf, Vbuf, mb, Mx);

    dim3 g2(HW / 64, CHG, B);                                // (64,2,4) = 512 blocks
    attn_kernel<<<g2, 256, 0, stream>>>(Kbuf, Vbuf, mb, Mx, out);
}

// Round 6
// 174.583 us; speedup vs baseline: 2.5163x; 1.0323x over previous
//
#include <hip/hip_runtime.h>
#include <math.h>

#define BN_EPS 1e-5f

constexpr int B  = 4;
constexpr int C  = 256;
constexpr int HW = 4096;   // 64*64
constexpr int CK = 64;
constexpr int CV = 256;
constexpr int CO = 320;    // CK + CV
constexpr int CHG = 2;     // channel groups in attn (128 ch each)

typedef short bf16x8 __attribute__((ext_vector_type(8)));
typedef float f32x4  __attribute__((ext_vector_type(4)));

__device__ __forceinline__ ushort f2bf(float f) {
    unsigned u = __float_as_uint(f);
    u += 0x7FFFu + ((u >> 16) & 1u);      // round to nearest even
    return (ushort)(u >> 16);
}

// byte-XOR swizzles (applied identically to pre-swizzled global source and
// LDS read -> involution, bijective within each 128-B row)
__device__ __forceinline__ int swzk(int r) {
    return (((r & 3) | ((((r >> 2) ^ (r >> 3)) & 1) << 2)) << 4);
}
__device__ __forceinline__ int swzv(int r) { return (r & 7) << 4; }

__device__ __forceinline__ void gload_lds16(const void* g, void* l) {
    __builtin_amdgcn_global_load_lds(
        (const __attribute__((address_space(1))) unsigned*)g,
        (__attribute__((address_space(3))) unsigned*)l, 16, 0, 0);
}

// ---------------------------------------------------------------------------
// Kernel 0: fold BN into Wk (row-scale), emit bf16 weights PRE-PACKED in
// kv_gemm's MFMA A-fragment order:
//   Wqp[wv][ks][mi][lane][e]  (lane = q*16+col, e = 0..7)
// so each kv_gemm fragment load is one fully-coalesced 1 KB wave load
// (R10 post-mortem: the old (row)*C layout made 16 lanes hit 16 different
// 512-B rows per inst = the scattered-load pattern that cost R9 2x).
// ---------------------------------------------------------------------------
__global__ __launch_bounds__(256) void wprep(
    const float* __restrict__ Wk, const float* __restrict__ bk,
    const float* __restrict__ gamma, const float* __restrict__ beta,
    const float* __restrict__ mean,  const float* __restrict__ var,
    const float* __restrict__ Wv, const float* __restrict__ bv,
    ushort* __restrict__ Wq, float* __restrict__ bq)
{
    const int co = blockIdx.x;
    const int c  = threadIdx.x;
    float w;
    if (co < CK) {
        float inv = gamma[co] * rsqrtf(var[co] + BN_EPS);
        w = Wk[co * C + c] * inv;
        if (c == 0) bq[co] = bk[co] * inv + (beta[co] - mean[co] * inv);
    } else {
        w = Wv[(co - CK) * C + c];
        if (c == 0) bq[co] = bv[co - CK];
    }
    // co = wv*80 + mi*16 + col ; c = ks*32 + q*8 + e
    const int wv  = co / 80, rem = co % 80;
    const int mi  = rem / 16, colw = rem % 16;
    const int ks  = c >> 5, qw = (c >> 3) & 3, e = c & 7;
    Wq[((((((wv * 8 + ks) * 5 + mi) * 4 + qw) * 16 + colw)) << 3) + e] = f2bf(w);
}

// ---------------------------------------------------------------------------
// Kernel 1: KV projection as MFMA GEMM + fused K-norms (Cauchy-Schwarz bound).
// R11: weight fragment loads are coalesced (packed Wq), rest unchanged.
// ---------------------------------------------------------------------------
__global__ __launch_bounds__(256) void kv_gemm(
    const float* __restrict__ x, const ushort* __restrict__ Wq,
    const float* __restrict__ bq,
    ushort* __restrict__ Kbuf, ushort* __restrict__ Vbuf,
    float* __restrict__ mb, unsigned* __restrict__ Mx)
{
    __shared__ __align__(16) ushort xt[32][C + 8];   // [hw][c] bf16, pad 8

    const int t    = threadIdx.x;
    const int lane = t & 63;
    const int wv   = t >> 6;
    const int q    = lane >> 4;
    const int col  = lane & 15;
    const int hw0  = blockIdx.x * 32;
    const int b    = blockIdx.y;

    const float* xb = x + (size_t)b * C * HW;

    // stage x tile: strided dword loads -> pack bf16x4 -> b64 LDS write
    {
        const int cq  = (t >> 5) * 4;    // 0,4,...,28
        const int hwo = t & 31;
#pragma unroll
        for (int pass = 0; pass < 8; pass++) {
            const int c0 = pass * 32;
            float a0 = xb[(size_t)(c0 + cq + 0) * HW + hw0 + hwo];
            float a1 = xb[(size_t)(c0 + cq + 1) * HW + hw0 + hwo];
            float a2 = xb[(size_t)(c0 + cq + 2) * HW + hw0 + hwo];
            float a3 = xb[(size_t)(c0 + cq + 3) * HW + hw0 + hwo];
            ushort4 u = make_ushort4(f2bf(a0), f2bf(a1), f2bf(a2), f2bf(a3));
            *(ushort4*)&xt[hwo][c0 + cq] = u;
        }
    }
    __syncthreads();

    f32x4 acc[5][2];
#pragma unroll
    for (int mi = 0; mi < 5; mi++)
#pragma unroll
        for (int nt = 0; nt < 2; nt++)
            acc[mi][nt] = (f32x4){0.f, 0.f, 0.f, 0.f};

#pragma unroll
    for (int ks = 0; ks < 8; ks++) {
        bf16x8 av[5], bvv[2];
#pragma unroll
        for (int mi = 0; mi < 5; mi++)
            av[mi] = *(const bf16x8*)(Wq + ((size_t)((wv * 8 + ks) * 5 + mi) << 9) + lane * 8);
#pragma unroll
        for (int nt = 0; nt < 2; nt++)
            bvv[nt] = *(const bf16x8*)&xt[nt * 16 + col][ks * 32 + q * 8];
#pragma unroll
        for (int mi = 0; mi < 5; mi++)
#pragma unroll
            for (int nt = 0; nt < 2; nt++)
                acc[mi][nt] = __builtin_amdgcn_mfma_f32_16x16x32_bf16(av[mi], bvv[nt], acc[mi][nt], 0, 0, 0);
    }

    float ssq[2] = {0.f, 0.f};
#pragma unroll
    for (int mi = 0; mi < 5; mi++) {
        const int cot = wv * 80 + mi * 16;
        float bi[4];
#pragma unroll
        for (int r = 0; r < 4; r++) bi[r] = bq[cot + q * 4 + r];
#pragma unroll
        for (int nt = 0; nt < 2; nt++) {
            const int hw = hw0 + nt * 16 + col;
            float v0 = acc[mi][nt][0] + bi[0];
            float v1 = acc[mi][nt][1] + bi[1];
            float v2 = acc[mi][nt][2] + bi[2];
            float v3 = acc[mi][nt][3] + bi[3];
            if (cot < CK) {           // K tiles: transposed b64 store
                ushort4 kk = make_ushort4(f2bf(v0), f2bf(v1), f2bf(v2), f2bf(v3));
                *(ushort4*)&Kbuf[((size_t)b * HW + hw) * CK + cot + q * 4] = kk;
                ssq[nt] += v0 * v0 + v1 * v1 + v2 * v2 + v3 * v3;
            } else {
                const int cv = cot - CK + q * 4;
                Vbuf[((size_t)b * CV + cv + 0) * HW + hw] = f2bf(v0);
                Vbuf[((size_t)b * CV + cv + 1) * HW + hw] = f2bf(v1);
                Vbuf[((size_t)b * CV + cv + 2) * HW + hw] = f2bf(v2);
                Vbuf[((size_t)b * CV + cv + 3) * HW + hw] = f2bf(v3);
            }
        }
    }

    if (wv == 0) {
        float mxn = 0.f;
#pragma unroll
        for (int nt = 0; nt < 2; nt++) {
            float ss = ssq[nt];
            ss += __shfl_xor(ss, 16, 64);
            ss += __shfl_xor(ss, 32, 64);
            float nr = sqrtf(ss);
            if (lane < 16) mb[(size_t)b * HW + hw0 + nt * 16 + col] = nr;
            mxn = fmaxf(mxn, nr);
        }
#pragma unroll
        for (int off = 1; off <= 32; off <<= 1)
            mxn = fmaxf(mxn, __shfl_xor(mxn, off, 64));
        if (t == 0) atomicMax(Mx + b, __float_as_uint(mxn));
    }
}

// ---------------------------------------------------------------------------
// Kernel 2: MFMA flash attention, bound-softmax. Zero-P-exchange (lane's S
// output IS its PV B-fragment) + LDS K/V staging via coalesced
// global_load_lds. UNCHANGED from R10 (verified, 90 us).
// ---------------------------------------------------------------------------
__global__ __launch_bounds__(256, 2) void attn_kernel(
    const ushort* __restrict__ Kbuf, const ushort* __restrict__ Vbuf,
    const float* __restrict__ mb, const unsigned* __restrict__ Mx,
    float* __restrict__ out)
{
    __shared__ __align__(16) ushort Kt[2][64 * 64];    // 8 KB per buf
    __shared__ __align__(16) ushort Vt[2][128 * 64];   // 16 KB per buf

    const int t    = threadIdx.x;
    const int lane = t & 63;
    const int wv   = t >> 6;          // 0..3 : i-group within block
    const int q    = lane >> 4;       // quad 0..3
    const int col  = lane & 15;

    // --- XCD-partition remap (bijective on the 512-block grid) ---
    const unsigned lin = blockIdx.x + 64u * (blockIdx.y + (unsigned)CHG * blockIdx.z);
    const int xcd   = lin & 7;
    const int s_    = lin >> 3;              // 0..63
    const int i0g   = s_ * 64;
    const int chg   = xcd & 1;
    const int b     = xcd >> 1;              // 0..3

    const int iw    = wv * 16 + col;         // local i row (0..63)
    const int jperm = (col >> 2) * 8 + (col & 3);  // j-row permutation base

    const ushort* Kb = Kbuf + (size_t)b * HW * CK;
    const ushort* Vb = Vbuf + (size_t)b * CV * HW;
    const int cbase = chg * 128;

    // Q B-frags: B[k=ck][n=i], n = col -> i = i0g + iw (one-time scattered)
    bf16x8 qa[2];
#pragma unroll
    for (int k = 0; k < 2; k++)
        qa[k] = *(const bf16x8*)(Kb + (size_t)(i0g + iw) * CK + k * 32 + q * 8);

    // per-row exp bound (Cauchy-Schwarz): one scalar per lane
    const float Mxf = __uint_as_float(Mx[b]);
    const float m_val = mb[(size_t)b * HW + i0g + iw] * Mxf;

    f32x4 Oacc[8];
#pragma unroll
    for (int mt = 0; mt < 8; mt++)
        Oacc[mt] = (f32x4){0.f, 0.f, 0.f, 0.f};

    float l_acc = 0.f;
    const f32x4 zf = (f32x4){0.f, 0.f, 0.f, 0.f};

    // ---- staging: K tile 8 KB (2 chunks/wave), V tile 16 KB (4 chunks/wave)
    // LDS dest linear (rule 21); global source pre-swizzled.
#define STAGE(BUF, JN)                                                         \
    {                                                                          \
        const int jn_s = (JN);                                                 \
        _Pragma("unroll")                                                      \
        for (int p = 0; p < 2; p++) {                                          \
            int off = (wv * 2 + p) * 1024 + lane * 16;                         \
            int r = off >> 7, cb = off & 127;                                  \
            const char* g = (const char*)Kb + (size_t)(jn_s + r) * 128         \
                            + (cb ^ swzk(r));                                  \
            gload_lds16(g, (char*)&Kt[BUF][0] + off);                          \
        }                                                                      \
        _Pragma("unroll")                                                      \
        for (int p = 0; p < 4; p++) {                                          \
            int off = (wv * 4 + p) * 1024 + lane * 16;                         \
            int r = off >> 7, cb = off & 127;                                  \
            const char* g = (const char*)Vb                                    \
                            + ((size_t)(cbase + r) * HW + jn_s) * 2            \
                            + (cb ^ swzv(r));                                  \
            gload_lds16(g, (char*)&Vt[BUF][0] + off);                          \
        }                                                                      \
    }

    // prologue: stage tile 0 into buf 0
    STAGE(0, 0);
    __syncthreads();

    int cur = 0;
    for (int j0 = 0; j0 < HW; j0 += 64) {
        // issue next tile's staging first (full-tile latency window)
        STAGE(cur ^ 1, (j0 + 64) & (HW - 1));

        const char* KtB = (const char*)&Kt[cur][0];
        const char* VtB = (const char*)&Vt[cur][0];

        // S^T = mfma(K, Q): K A-frags from LDS (jperm rows, swizzled)
        f32x4 S[4];
        __builtin_amdgcn_s_setprio(1);
#pragma unroll
        for (int nt = 0; nt < 4; nt++) {
            const int jr = jperm + (nt >> 1) * 32 + (nt & 1) * 4;
            bf16x8 k0 = *(const bf16x8*)(KtB + jr * 128 + ((q * 16) ^ swzk(jr)));
            bf16x8 k1 = *(const bf16x8*)(KtB + jr * 128 + ((64 + q * 16) ^ swzk(jr)));
            S[nt] = __builtin_amdgcn_mfma_f32_16x16x32_bf16(k0, qa[0], zf, 0, 0, 0);
            S[nt] = __builtin_amdgcn_mfma_f32_16x16x32_bf16(k1, qa[1], S[nt], 0, 0, 0);
        }
        __builtin_amdgcn_s_setprio(0);

        // exp + pack into PV B-fragments (register P, verified layout)
        bf16x8 w0, w1;
#pragma unroll
        for (int nt = 0; nt < 4; nt++) {
            float p0 = __expf(S[nt][0] - m_val);
            float p1 = __expf(S[nt][1] - m_val);
            float p2 = __expf(S[nt][2] - m_val);
            float p3 = __expf(S[nt][3] - m_val);
            l_acc += (p0 + p1) + (p2 + p3);
            if (nt == 0) {
                w0[0] = (short)f2bf(p0); w0[1] = (short)f2bf(p1);
                w0[2] = (short)f2bf(p2); w0[3] = (short)f2bf(p3);
            } else if (nt == 1) {
                w0[4] = (short)f2bf(p0); w0[5] = (short)f2bf(p1);
                w0[6] = (short)f2bf(p2); w0[7] = (short)f2bf(p3);
            } else if (nt == 2) {
                w1[0] = (short)f2bf(p0); w1[1] = (short)f2bf(p1);
                w1[2] = (short)f2bf(p2); w1[3] = (short)f2bf(p3);
            } else {
                w1[4] = (short)f2bf(p0); w1[5] = (short)f2bf(p1);
                w1[6] = (short)f2bf(p2); w1[7] = (short)f2bf(p3);
            }
        }

        // PV: V B-frags from LDS (row = c, swizzled), 2 MFMA per mt
        __builtin_amdgcn_s_setprio(1);
#pragma unroll
        for (int mt = 0; mt < 8; mt++) {
            const int vr = mt * 16 + col;
            bf16x8 v0 = *(const bf16x8*)(VtB + vr * 128 + ((q * 16) ^ swzv(vr)));
            bf16x8 v1 = *(const bf16x8*)(VtB + vr * 128 + ((64 + q * 16) ^ swzv(vr)));
            Oacc[mt] = __builtin_amdgcn_mfma_f32_16x16x32_bf16(v0, w0, Oacc[mt], 0, 0, 0);
            Oacc[mt] = __builtin_amdgcn_mfma_f32_16x16x32_bf16(v1, w1, Oacc[mt], 0, 0, 0);
        }
        __builtin_amdgcn_s_setprio(0);

        __syncthreads();   // buf ready-to-overwrite + next stage completed
        cur ^= 1;
    }
#undef STAGE

    // row sum l for i = i0g+iw: reduce across the 4 quad-groups
    l_acc += __shfl_xor(l_acc, 16, 64);
    l_acc += __shfl_xor(l_acc, 32, 64);
    const float inv = 1.0f / l_acc;

    // O store (single-writer; chg disjoint): fused division
    float* ob = out + (size_t)b * CV * HW;
#pragma unroll
    for (int mt = 0; mt < 8; mt++)
#pragma unroll
        for (int r = 0; r < 4; r++)
            ob[(size_t)(cbase + mt * 16 + q * 4 + r) * HW + i0g + iw] = Oacc[mt][r] * inv;
}

// ---------------------------------------------------------------------------
extern "C" void kernel_launch(void* const* d_in, const int* in_sizes, int n_in,
                              void* d_out, int out_size, void* d_ws, size_t ws_size,
                              hipStream_t stream)
{
    const float* x     = (const float*)d_in[0];
    const float* Wk    = (const float*)d_in[1];
    const float* bk    = (const float*)d_in[2];
    const float* gamma = (const float*)d_in[3];
    const float* beta  = (const float*)d_in[4];
    const float* mean  = (const float*)d_in[5];
    const float* var   = (const float*)d_in[6];
    const float* Wv    = (const float*)d_in[7];
    const float* bv    = (const float*)d_in[8];
    float* out = (float*)d_out;

    ushort*   Kbuf = (ushort*)d_ws;                          // [B][HW][CK]  2 MB
    ushort*   Vbuf = Kbuf + (size_t)B * HW * CK;             // [B][CV][HW]  8.4 MB
    ushort*   Wq   = Vbuf + (size_t)B * CV * HW;             // [320][256] packed, 160 KB
    float*    bq   = (float*)(Wq + (size_t)CO * C);          // [320]
    float*    mb   = bq + CO;                                // [B][HW]
    unsigned* Mx   = (unsigned*)(mb + (size_t)B * HW);       // [B]

    hipMemsetAsync(Mx, 0, B * sizeof(unsigned), stream);

    wprep<<<dim3(CO), 256, 0, stream>>>(Wk, bk, gamma, beta, mean, var, Wv, bv, Wq, bq);

    kv_gemm<<<dim3(HW / 32, B), 256, 0, stream>>>(x, Wq, bq, Kbuf, Vbuf, mb, Mx);

    dim3 g2(HW / 64, CHG, B);                                // (64,2,4) = 512 blocks
    attn_kernel<<<g2, 256, 0, stream>>>(Kbuf, Vbuf, mb, Mx, out);
}